// Round 3
// baseline (282.871 us; speedup 1.0000x reference)
//
#include <hip/hip_runtime.h>
#include <cstdint>
#include <cmath>

#define LN_EPS 1e-6f

// ---- workspace layout (float offsets) ----
#define N_QCH 24u                      // q partial chunks (32 c each)
#define O_QPART 0u                     // [24][3072]
#define O_Q     73728u                 // [3072] scaled q
#define O_WK    76800u                 // wk_eff [768][12]
#define O_PLOG  86016u                 // partial logits [4][96][4096]
#define O_PHP   1658880u               // ph partials [32][96][768]
#define N_SC    32
#define O_PH    4018176u               // [96][768]
#define O_CTXP  4091904u               // ctx partials [12][8][3072]
#define N_CCH   12
#define O_CTX   4386816u               // [8][3072]
#define O_OUTP  4411392u               // out partials [48][8][768]
#define N_ICH   48
// end: 4706304 floats = 18.8 MB (ws is ~384 MiB)

__device__ __forceinline__ float waveReduceSum(float v) {
#pragma unroll
    for (int o = 32; o >= 1; o >>= 1) v += __shfl_xor(v, o, 64);
    return v;
}
__device__ __forceinline__ float waveReduceMax(float v) {
#pragma unroll
    for (int o = 32; o >= 1; o >>= 1) v = fmaxf(v, __shfl_xor(v, o, 64));
    return v;
}

// K1: q partials: q_part[ch][h*256+d] = sum_{c in chunk} pq[c]*Wq[c, h*256+d]
__global__ __launch_bounds__(256) void k1_qpart(const float* __restrict__ pq,
                                                const float* __restrict__ Wq,
                                                float* __restrict__ ws) {
    int h = blockIdx.x % 12;
    int ch = blockIdx.x / 12;          // 24 chunks of 32 c
    int tid = threadIdx.x;
    int col = h * 256 + tid;
    int c0 = ch * 32;
    float acc = 0.f;
#pragma unroll 8
    for (int i = 0; i < 32; ++i) {
        int c = c0 + i;
        acc += pq[c] * Wq[c * 3072 + col];
    }
    ws[O_QPART + ch * 3072 + col] = acc;
}

// K1b: reduce q partials, add bq, apply scale * softplus(per_dim_scale)
__global__ __launch_bounds__(256) void k1b_qreduce(const float* __restrict__ bq,
                                                   const float* __restrict__ pds,
                                                   float* __restrict__ ws) {
    int j = blockIdx.x * 256 + threadIdx.x;   // < 3072
    float acc = bq[j];
#pragma unroll
    for (unsigned ch = 0; ch < N_QCH; ++ch) acc += ws[O_QPART + ch * 3072 + j];
    float x = pds[j & 255];
    float sp = (x > 20.f) ? x : log1pf(expf(x));
    const float scale = 1.442695041f / 16.0f;  // r_softplus_0 / sqrt(256)
    ws[O_Q + j] = acc * scale * sp;
}

// K2: wk_eff[c][h] = sum_d Wk[c, h*256+d]*q[h,d]
// one block per c-row; wave w handles heads {3w, 3w+1, 3w+2} via float4 dots.
// (bk folds to a per-row softmax-invariant constant -> dropped)
__global__ __launch_bounds__(256) void k2_wkeff(const float* __restrict__ Wk,
                                                float* __restrict__ ws) {
    int c = blockIdx.x;                // 768
    int tid = threadIdx.x;
    int w = tid >> 6, lane = tid & 63;
    const float4* wk = reinterpret_cast<const float4*>(Wk + (size_t)c * 3072);
    const float4* qv = reinterpret_cast<const float4*>(ws + O_Q);
#pragma unroll
    for (int i = 0; i < 3; ++i) {
        int h = w * 3 + i;
        float4 a = wk[h * 64 + lane];
        float4 b = qv[h * 64 + lane];
        float d = a.x * b.x + a.y * b.y + a.z * b.z + a.w * b.w;
        d = waveReduceSum(d);
        if (lane == 0) ws[O_WK + c * 12 + h] = d;
    }
}

// K3: partial logits. block = (b, s-tile of 64 rows, c-quarter of 192).
// ALL 12 hidden float4 loads issued up front (one latency exposure/block),
// then 2 chunks of [LDS swizzled write -> barrier -> compute].
// XOR swizzle: store tile4[r*24 + (j^(r&7))]; lane=row reads conflict-free.
__global__ __launch_bounds__(256, 4) void k3_logits(const float* __restrict__ hidden,
                                                    float* __restrict__ ws) {
    __shared__ float4 tile4[1536];     // 24 KB: 64 rows x 24 float4 (96 c), swizzled
    __shared__ float4 wkb4[576];       // 9 KB: 192 c x 12 h
    int blk = blockIdx.x;              // 2048 = 8 b * 64 stiles * 4 quarters
    int q = blk & 3;
    int st = (blk >> 2) & 63;
    int b = blk >> 8;
    int s0 = st * 64;
    const float* hb = hidden + (size_t)(b * 4096 + s0) * 768;
    const float4* wkg4 = reinterpret_cast<const float4*>(ws + O_WK);
    int tid = threadIdx.x;
    int w = tid >> 6, lane = tid & 63;
    int r = (6 * 256 + tid) / 24 - 64;  // dummy init removed below
    // decode (r,j) for this thread's 6 slots (same for both chunks)
    int rr[6], jj6[6];
#pragma unroll
    for (int it = 0; it < 6; ++it) {
        int idx = it * 256 + tid;
        rr[it] = idx / 24;
        jj6[it] = idx % 24;
    }
    // prefetch both chunks' hidden data into registers
    float4 v0[6], v1[6];
#pragma unroll
    for (int it = 0; it < 6; ++it)
        v0[it] = reinterpret_cast<const float4*>(hb + rr[it] * 768 + q * 192)[jj6[it]];
#pragma unroll
    for (int it = 0; it < 6; ++it)
        v1[it] = reinterpret_cast<const float4*>(hb + rr[it] * 768 + q * 192 + 96)[jj6[it]];
    // stage wk slice for both chunks: 192 c x 12 h = 576 float4
    for (int i = tid; i < 576; i += 256) wkb4[i] = wkg4[q * 576 + i];

    float acc[12];
#pragma unroll
    for (int h = 0; h < 12; ++h) acc[h] = 0.f;

#pragma unroll
    for (int cph = 0; cph < 2; ++cph) {
#pragma unroll
        for (int it = 0; it < 6; ++it)
            tile4[rr[it] * 24 + (jj6[it] ^ (rr[it] & 7))] = cph ? v1[it] : v0[it];
        __syncthreads();
#pragma unroll
        for (int jj = 0; jj < 6; ++jj) {
            int jcol = w * 6 + jj;
            float4 x = tile4[lane * 24 + (jcol ^ (lane & 7))];
            const float4* wr = &wkb4[cph * 288 + jcol * 12];
            float xc[4] = {x.x, x.y, x.z, x.w};
#pragma unroll
            for (int cc = 0; cc < 4; ++cc) {
                float4 w0 = wr[cc * 3 + 0], w1 = wr[cc * 3 + 1], w2 = wr[cc * 3 + 2];
                acc[0] += xc[cc] * w0.x;  acc[1] += xc[cc] * w0.y;  acc[2]  += xc[cc] * w0.z;  acc[3]  += xc[cc] * w0.w;
                acc[4] += xc[cc] * w1.x;  acc[5] += xc[cc] * w1.y;  acc[6]  += xc[cc] * w1.z;  acc[7]  += xc[cc] * w1.w;
                acc[8] += xc[cc] * w2.x;  acc[9] += xc[cc] * w2.y;  acc[10] += xc[cc] * w2.z;  acc[11] += xc[cc] * w2.w;
            }
        }
        __syncthreads();
    }
    float* red = reinterpret_cast<float*>(tile4);   // alias tile (3072 <= 6144 floats)
#pragma unroll
    for (int h = 0; h < 12; ++h) red[(w * 12 + h) * 64 + lane] = acc[h];
    __syncthreads();
    float* plog = ws + O_PLOG;
    for (int idx = tid; idx < 768; idx += 256) {
        int h = idx / 64, r2 = idx & 63;
        float v = red[(0 + h) * 64 + r2] + red[(12 + h) * 64 + r2] +
                  red[(24 + h) * 64 + r2] + red[(36 + h) * 64 + r2];
        plog[(size_t)q * 393216 + (size_t)(b * 12 + h) * 4096 + s0 + r2] = v;
    }
    (void)r;
}

// K4: sum the four c-quarter partials, softmax over s=4096, write attn to d_out
__global__ __launch_bounds__(256) void k4_softmax(const float* __restrict__ ws,
                                                  float* __restrict__ attn) {
    __shared__ float sh[4];
    int row = blockIdx.x;              // 96 = 8*12
    const float4* p0 = reinterpret_cast<const float4*>(ws + O_PLOG + (size_t)row * 4096);
    const float4* p1 = p0 + 98304;     // +393216 floats
    const float4* p2 = p0 + 196608;
    const float4* p3 = p0 + 294912;
    float* base = attn + (size_t)row * 4096;
    int tid = threadIdx.x;
    float4 x[4];
#pragma unroll
    for (int t = 0; t < 4; ++t) {
        float4 a = p0[t * 256 + tid], c = p1[t * 256 + tid];
        float4 d = p2[t * 256 + tid], e = p3[t * 256 + tid];
        x[t].x = (a.x + c.x) + (d.x + e.x);
        x[t].y = (a.y + c.y) + (d.y + e.y);
        x[t].z = (a.z + c.z) + (d.z + e.z);
        x[t].w = (a.w + c.w) + (d.w + e.w);
    }
    float m = -1e30f;
#pragma unroll
    for (int t = 0; t < 4; ++t)
        m = fmaxf(m, fmaxf(fmaxf(x[t].x, x[t].y), fmaxf(x[t].z, x[t].w)));
    m = waveReduceMax(m);
    if ((tid & 63) == 0) sh[tid >> 6] = m;
    __syncthreads();
    m = fmaxf(fmaxf(sh[0], sh[1]), fmaxf(sh[2], sh[3]));
    __syncthreads();
    float s = 0.f;
#pragma unroll
    for (int t = 0; t < 4; ++t) {
        x[t].x = expf(x[t].x - m); x[t].y = expf(x[t].y - m);
        x[t].z = expf(x[t].z - m); x[t].w = expf(x[t].w - m);
        s += x[t].x + x[t].y + x[t].z + x[t].w;
    }
    s = waveReduceSum(s);
    if ((tid & 63) == 0) sh[tid >> 6] = s;
    __syncthreads();
    s = sh[0] + sh[1] + sh[2] + sh[3];
    float inv = 1.0f / s;
#pragma unroll
    for (int t = 0; t < 4; ++t) {
        x[t].x *= inv; x[t].y *= inv; x[t].z *= inv; x[t].w *= inv;
        reinterpret_cast<float4*>(base)[t * 256 + tid] = x[t];
    }
}

// K5: ph partials. wave w handles s = s0 + 4g + w -> hidden loads are lane-contiguous
// float4 (16B/lane), attn loads wave-uniform scalars. Cross-wave LDS reduce at end.
__global__ __launch_bounds__(256) void k5_phpart(const float* __restrict__ hidden,
                                                 const float* __restrict__ attn,
                                                 float* __restrict__ ws) {
    __shared__ float4 sh4[12 * 4 * 64];    // 48 KB
    int blk = blockIdx.x;              // 768 = 8 b * 3 ct * 32 sc
    int sc = blk & 31;
    int ct = (blk >> 5) % 3;
    int b = blk / 96;
    int tid = threadIdx.x;
    int w = tid >> 6, lane = tid & 63;
    int c = ct * 256 + lane * 4;
    int s0 = sc * 128;
    const float* hb = hidden + (size_t)(b * 4096 + s0) * 768 + c;
    const float* ab = attn + (size_t)b * 49152 + s0 + w;
    float4 acc[12];
#pragma unroll
    for (int h = 0; h < 12; ++h) acc[h] = make_float4(0.f, 0.f, 0.f, 0.f);
    for (int g = 0; g < 32; ++g) {
        float4 x = *reinterpret_cast<const float4*>(hb + (size_t)(g * 4 + w) * 768);
        float a[12];
#pragma unroll
        for (int h = 0; h < 12; ++h) a[h] = ab[h * 4096 + g * 4];
#pragma unroll
        for (int h = 0; h < 12; ++h) {
            acc[h].x += a[h] * x.x; acc[h].y += a[h] * x.y;
            acc[h].z += a[h] * x.z; acc[h].w += a[h] * x.w;
        }
    }
#pragma unroll
    for (int h = 0; h < 12; ++h) sh4[(h * 4 + w) * 64 + lane] = acc[h];
    __syncthreads();
    float* php = ws + O_PHP;
#pragma unroll
    for (int i = 0; i < 3; ++i) {
        int h = w * 3 + i;
        float4 a = sh4[(h * 4 + 0) * 64 + lane];
        float4 b2 = sh4[(h * 4 + 1) * 64 + lane];
        float4 c2 = sh4[(h * 4 + 2) * 64 + lane];
        float4 d = sh4[(h * 4 + 3) * 64 + lane];
        float4 r;
        r.x = (a.x + b2.x) + (c2.x + d.x);
        r.y = (a.y + b2.y) + (c2.y + d.y);
        r.z = (a.z + b2.z) + (c2.z + d.z);
        r.w = (a.w + b2.w) + (c2.w + d.w);
        *reinterpret_cast<float4*>(php + (size_t)(sc * 96 + b * 12 + h) * 768 + c) = r;
    }
}

// K6: reduce ph partials over the 32 s-chunks
__global__ __launch_bounds__(256) void k6_phreduce(float* __restrict__ ws) {
    int gid = blockIdx.x * 256 + threadIdx.x;   // < 73728
    const float* php = ws + O_PHP;
    float s = 0.f;
#pragma unroll
    for (int sc = 0; sc < N_SC; ++sc) s += php[(size_t)sc * 73728 + gid];
    ws[O_PH + gid] = s;
}

// K7: ctx partials: ctx_part[cch][b][j] = sum_{c in chunk} ph[b, h(j), c] * Wv[c, j]
__global__ __launch_bounds__(256) void k7_ctxpart(const float* __restrict__ Wv,
                                                  float* __restrict__ ws) {
    int blk = blockIdx.x;              // 144 = 12 jt * 12 cch
    int jt = blk % 12, cch = blk / 12;
    int tid = threadIdx.x;
    int j = jt * 256 + tid;
    int h = jt;                        // j-tile of 256 aligns with heads
    const float* ph = ws + O_PH;
    float acc[8];
#pragma unroll
    for (int b = 0; b < 8; ++b) acc[b] = 0.f;
    for (int cc = 0; cc < 64; ++cc) {
        int c = cch * 64 + cc;
        float wv = Wv[(size_t)c * 3072 + j];
#pragma unroll
        for (int b = 0; b < 8; ++b) acc[b] += ph[(b * 12 + h) * 768 + c] * wv;
    }
#pragma unroll
    for (int b = 0; b < 8; ++b)
        ws[O_CTXP + (size_t)(cch * 8 + b) * 3072 + j] = acc[b];
}

// K7b: ctx[b][i] = sum_cch ctx_part + bv[i]
__global__ __launch_bounds__(256) void k7b_ctxreduce(const float* __restrict__ bv,
                                                     float* __restrict__ ws) {
    int gid = blockIdx.x * 256 + threadIdx.x;   // < 24576
    int b = gid / 3072, i = gid % 3072;
    float s = bv[i];
#pragma unroll
    for (int cch = 0; cch < N_CCH; ++cch) s += ws[O_CTXP + (size_t)(cch * 8 + b) * 3072 + i];
    ws[O_CTX + gid] = s;
}

// K8: out partials: out_part[ich][b][j] = sum_{i in chunk} ctx[b][i]*Wp[i,j]
__global__ __launch_bounds__(256) void k8_outpart(const float* __restrict__ Wp,
                                                  float* __restrict__ ws) {
    int blk = blockIdx.x;              // 144 = 3 jt * 48 ich
    int jt = blk % 3, ich = blk / 3;
    int tid = threadIdx.x;
    int j = jt * 256 + tid;
    const float* ctx = ws + O_CTX;
    float acc[8];
#pragma unroll
    for (int b = 0; b < 8; ++b) acc[b] = 0.f;
    for (int ii = 0; ii < 64; ++ii) {
        int i = ich * 64 + ii;
        float wp = Wp[(size_t)i * 768 + j];
#pragma unroll
        for (int b = 0; b < 8; ++b) acc[b] += ctx[b * 3072 + i] * wp;
    }
#pragma unroll
    for (int b = 0; b < 8; ++b)
        ws[O_OUTP + (size_t)(ich * 8 + b) * 768 + j] = acc[b];
}

// K9: reduce out partials + bp, layernorm, write pooled
__global__ __launch_bounds__(256) void k9_ln(const float* __restrict__ bp,
                                             const float* __restrict__ ln_w,
                                             const float* __restrict__ ln_b,
                                             const float* __restrict__ ws,
                                             float* __restrict__ pooled) {
    __shared__ float sh[8];
    int b = blockIdx.x, tid = threadIdx.x;
    const float* op = ws + O_OUTP;
    float vals[3];
    float lsum = 0.f, lsq = 0.f;
#pragma unroll
    for (int t = 0; t < 3; ++t) {
        int j = t * 256 + tid;
        float v = bp[j];
#pragma unroll
        for (int ich = 0; ich < N_ICH; ++ich) v += op[(size_t)(ich * 8 + b) * 768 + j];
        vals[t] = v; lsum += v; lsq += v * v;
    }
    lsum = waveReduceSum(lsum);
    lsq = waveReduceSum(lsq);
    if ((tid & 63) == 0) { sh[tid >> 6] = lsum; sh[4 + (tid >> 6)] = lsq; }
    __syncthreads();
    float mean = (sh[0] + sh[1] + sh[2] + sh[3]) * (1.f / 768.f);
    float var = (sh[4] + sh[5] + sh[6] + sh[7]) * (1.f / 768.f) - mean * mean;
    float inv = rsqrtf(var + LN_EPS);
#pragma unroll
    for (int t = 0; t < 3; ++t) {
        int j = t * 256 + tid;
        pooled[b * 768 + j] = (vals[t] - mean) * inv * (ln_w[j] + 1.f) + ln_b[j];
    }
}

extern "C" void kernel_launch(void* const* d_in, const int* in_sizes, int n_in,
                              void* d_out, int out_size, void* d_ws, size_t ws_size,
                              hipStream_t stream) {
    const float* hidden = (const float*)d_in[0];
    const float* pq     = (const float*)d_in[1];
    const float* Wq     = (const float*)d_in[2];
    const float* bq     = (const float*)d_in[3];
    const float* Wk     = (const float*)d_in[4];
    const float* Wv     = (const float*)d_in[6];
    const float* bv     = (const float*)d_in[7];
    const float* Wp     = (const float*)d_in[8];
    const float* bp     = (const float*)d_in[9];
    const float* pds    = (const float*)d_in[10];
    const float* ln_w   = (const float*)d_in[11];
    const float* ln_b   = (const float*)d_in[12];
    float* out = (float*)d_out;
    float* ws  = (float*)d_ws;
    float* pooled = out;          // (8,1,768) = 6144 floats
    float* attn   = out + 6144;   // (8,12,1,4096) = 393216 floats

    k1_qpart   <<<288, 256, 0, stream>>>(pq, Wq, ws);
    k1b_qreduce<<<12, 256, 0, stream>>>(bq, pds, ws);
    k2_wkeff   <<<768, 256, 0, stream>>>(Wk, ws);
    k3_logits  <<<2048, 256, 0, stream>>>(hidden, ws);
    k4_softmax <<<96, 256, 0, stream>>>(ws, attn);
    k5_phpart  <<<768, 256, 0, stream>>>(hidden, attn, ws);
    k6_phreduce<<<288, 256, 0, stream>>>(ws);
    k7_ctxpart <<<144, 256, 0, stream>>>(Wv, ws);
    k7b_ctxreduce<<<96, 256, 0, stream>>>(bv, ws);
    k8_outpart <<<144, 256, 0, stream>>>(Wp, ws);
    k9_ln      <<<8, 256, 0, stream>>>(bp, ln_w, ln_b, ws, pooled);
}

// Round 4
// 271.840 us; speedup vs baseline: 1.0406x; 1.0406x over previous
//
#include <hip/hip_runtime.h>
#include <cstdint>
#include <cmath>

#define LN_EPS 1e-6f

// ---- workspace layout (float offsets) ----
#define N_QCH 24u                      // q partial chunks (32 c each)
#define O_QPART 0u                     // [24][3072]
#define O_Q     73728u                 // [3072] scaled q
#define O_WK    76800u                 // wk_eff [768][12]
#define O_PLOG  86016u                 // partial logits [4][96][4096]
#define O_PHP   1658880u               // ph partials [32][96][768]
#define N_SC    32
#define O_CTXP  4091904u               // ctx partials [12][8][3072]
#define N_CCH   12
#define O_OUTP  4411392u               // out partials [48][8][768]
#define N_ICH   48
// end: 4706304 floats = 18.8 MB (ws is ~384 MiB)

__device__ __forceinline__ float waveReduceSum(float v) {
#pragma unroll
    for (int o = 32; o >= 1; o >>= 1) v += __shfl_xor(v, o, 64);
    return v;
}
__device__ __forceinline__ float waveReduceMax(float v) {
#pragma unroll
    for (int o = 32; o >= 1; o >>= 1) v = fmaxf(v, __shfl_xor(v, o, 64));
    return v;
}

// K1: q partials: q_part[ch][h*256+d] = sum_{c in chunk} pq[c]*Wq[c, h*256+d]
__global__ __launch_bounds__(256) void k1_qpart(const float* __restrict__ pq,
                                                const float* __restrict__ Wq,
                                                float* __restrict__ ws) {
    int h = blockIdx.x % 12;
    int ch = blockIdx.x / 12;          // 24 chunks of 32 c
    int tid = threadIdx.x;
    int col = h * 256 + tid;
    int c0 = ch * 32;
    float acc = 0.f;
#pragma unroll 8
    for (int i = 0; i < 32; ++i) {
        int c = c0 + i;
        acc += pq[c] * Wq[c * 3072 + col];
    }
    ws[O_QPART + ch * 3072 + col] = acc;
}

// K1b: reduce q partials, add bq, apply scale * softplus(per_dim_scale)
__global__ __launch_bounds__(256) void k1b_qreduce(const float* __restrict__ bq,
                                                   const float* __restrict__ pds,
                                                   float* __restrict__ ws) {
    int j = blockIdx.x * 256 + threadIdx.x;   // < 3072
    float acc = bq[j];
#pragma unroll
    for (unsigned ch = 0; ch < N_QCH; ++ch) acc += ws[O_QPART + ch * 3072 + j];
    float x = pds[j & 255];
    float sp = (x > 20.f) ? x : log1pf(expf(x));
    const float scale = 1.442695041f / 16.0f;  // r_softplus_0 / sqrt(256)
    ws[O_Q + j] = acc * scale * sp;
}

// K2: wk_eff[c][h] = sum_d Wk[c, h*256+d]*q[h,d]
// one block per c-row; wave w handles heads {3w, 3w+1, 3w+2} via float4 dots.
// (bk folds to a per-row softmax-invariant constant -> dropped)
__global__ __launch_bounds__(256) void k2_wkeff(const float* __restrict__ Wk,
                                                float* __restrict__ ws) {
    int c = blockIdx.x;                // 768
    int tid = threadIdx.x;
    int w = tid >> 6, lane = tid & 63;
    const float4* wk = reinterpret_cast<const float4*>(Wk + (size_t)c * 3072);
    const float4* qv = reinterpret_cast<const float4*>(ws + O_Q);
#pragma unroll
    for (int i = 0; i < 3; ++i) {
        int h = w * 3 + i;
        float4 a = wk[h * 64 + lane];
        float4 b = qv[h * 64 + lane];
        float d = a.x * b.x + a.y * b.y + a.z * b.z + a.w * b.w;
        d = waveReduceSum(d);
        if (lane == 0) ws[O_WK + c * 12 + h] = d;
    }
}

// K3: partial logits. block = (b, s-tile of 64 rows, c-quarter of 192 = 2 chunks of 96).
// Software pipeline: prefetch chunk0 -> [LDS write | issue chunk1 loads | barrier |
// compute | barrier]. Only 6 float4 prefetch regs live at once.
// XOR swizzle: store tile4[r*24 + (j^(r&7))]; lane=row reads conflict-free.
__global__ __launch_bounds__(256) void k3_logits(const float* __restrict__ hidden,
                                                 float* __restrict__ ws) {
    __shared__ float4 tile4[1536];     // 24 KB: 64 rows x 24 float4 (96 c), swizzled
    __shared__ float4 wkb4[576];       // 9 KB: 192 c x 12 h (both chunks)
    int blk = blockIdx.x;              // 2048 = 8 b * 64 stiles * 4 quarters
    int q = blk & 3;
    int st = (blk >> 2) & 63;
    int b = blk >> 8;
    int s0 = st * 64;
    const float* hb = hidden + (size_t)(b * 4096 + s0) * 768;
    const float4* wkg4 = reinterpret_cast<const float4*>(ws + O_WK);
    int tid = threadIdx.x;
    int w = tid >> 6, lane = tid & 63;
    int rr[6], jj6[6];
#pragma unroll
    for (int it = 0; it < 6; ++it) {
        int idx = it * 256 + tid;
        rr[it] = idx / 24;
        jj6[it] = idx % 24;
    }
    // stage wk slice for both chunks: 192 c x 12 h = 576 float4
    for (int i = tid; i < 576; i += 256) wkb4[i] = wkg4[q * 576 + i];
    // prefetch chunk 0
    float4 v[6];
#pragma unroll
    for (int it = 0; it < 6; ++it)
        v[it] = reinterpret_cast<const float4*>(hb + rr[it] * 768 + q * 192)[jj6[it]];

    float acc[12];
#pragma unroll
    for (int h = 0; h < 12; ++h) acc[h] = 0.f;

#pragma unroll
    for (int cph = 0; cph < 2; ++cph) {
#pragma unroll
        for (int it = 0; it < 6; ++it)
            tile4[rr[it] * 24 + (jj6[it] ^ (rr[it] & 7))] = v[it];
        if (cph == 0) {
            // issue chunk-1 loads; they complete during chunk-0 compute
#pragma unroll
            for (int it = 0; it < 6; ++it)
                v[it] = reinterpret_cast<const float4*>(hb + rr[it] * 768 + q * 192 + 96)[jj6[it]];
        }
        __syncthreads();
#pragma unroll
        for (int jj = 0; jj < 6; ++jj) {
            int jcol = w * 6 + jj;
            float4 x = tile4[lane * 24 + (jcol ^ (lane & 7))];
            const float4* wr = &wkb4[cph * 288 + jcol * 12];
            float xc[4] = {x.x, x.y, x.z, x.w};
#pragma unroll
            for (int cc = 0; cc < 4; ++cc) {
                float4 w0 = wr[cc * 3 + 0], w1 = wr[cc * 3 + 1], w2 = wr[cc * 3 + 2];
                acc[0] += xc[cc] * w0.x;  acc[1] += xc[cc] * w0.y;  acc[2]  += xc[cc] * w0.z;  acc[3]  += xc[cc] * w0.w;
                acc[4] += xc[cc] * w1.x;  acc[5] += xc[cc] * w1.y;  acc[6]  += xc[cc] * w1.z;  acc[7]  += xc[cc] * w1.w;
                acc[8] += xc[cc] * w2.x;  acc[9] += xc[cc] * w2.y;  acc[10] += xc[cc] * w2.z;  acc[11] += xc[cc] * w2.w;
            }
        }
        __syncthreads();
    }
    float* red = reinterpret_cast<float*>(tile4);   // alias tile (3072 <= 6144 floats)
#pragma unroll
    for (int h = 0; h < 12; ++h) red[(w * 12 + h) * 64 + lane] = acc[h];
    __syncthreads();
    float* plog = ws + O_PLOG;
    for (int idx = tid; idx < 768; idx += 256) {
        int h = idx / 64, r2 = idx & 63;
        float v2 = red[(0 + h) * 64 + r2] + red[(12 + h) * 64 + r2] +
                   red[(24 + h) * 64 + r2] + red[(36 + h) * 64 + r2];
        plog[(size_t)q * 393216 + (size_t)(b * 12 + h) * 4096 + s0 + r2] = v2;
    }
}

// K4: sum the four c-quarter partials, softmax over s=4096, write attn to d_out
__global__ __launch_bounds__(256) void k4_softmax(const float* __restrict__ ws,
                                                  float* __restrict__ attn) {
    __shared__ float sh[4];
    int row = blockIdx.x;              // 96 = 8*12
    const float4* p0 = reinterpret_cast<const float4*>(ws + O_PLOG + (size_t)row * 4096);
    const float4* p1 = p0 + 98304;     // +393216 floats
    const float4* p2 = p0 + 196608;
    const float4* p3 = p0 + 294912;
    float* base = attn + (size_t)row * 4096;
    int tid = threadIdx.x;
    float4 x[4];
#pragma unroll
    for (int t = 0; t < 4; ++t) {
        float4 a = p0[t * 256 + tid], c = p1[t * 256 + tid];
        float4 d = p2[t * 256 + tid], e = p3[t * 256 + tid];
        x[t].x = (a.x + c.x) + (d.x + e.x);
        x[t].y = (a.y + c.y) + (d.y + e.y);
        x[t].z = (a.z + c.z) + (d.z + e.z);
        x[t].w = (a.w + c.w) + (d.w + e.w);
    }
    float m = -1e30f;
#pragma unroll
    for (int t = 0; t < 4; ++t)
        m = fmaxf(m, fmaxf(fmaxf(x[t].x, x[t].y), fmaxf(x[t].z, x[t].w)));
    m = waveReduceMax(m);
    if ((tid & 63) == 0) sh[tid >> 6] = m;
    __syncthreads();
    m = fmaxf(fmaxf(sh[0], sh[1]), fmaxf(sh[2], sh[3]));
    __syncthreads();
    float s = 0.f;
#pragma unroll
    for (int t = 0; t < 4; ++t) {
        x[t].x = expf(x[t].x - m); x[t].y = expf(x[t].y - m);
        x[t].z = expf(x[t].z - m); x[t].w = expf(x[t].w - m);
        s += x[t].x + x[t].y + x[t].z + x[t].w;
    }
    s = waveReduceSum(s);
    if ((tid & 63) == 0) sh[tid >> 6] = s;
    __syncthreads();
    s = sh[0] + sh[1] + sh[2] + sh[3];
    float inv = 1.0f / s;
#pragma unroll
    for (int t = 0; t < 4; ++t) {
        x[t].x *= inv; x[t].y *= inv; x[t].z *= inv; x[t].w *= inv;
        reinterpret_cast<float4*>(base)[t * 256 + tid] = x[t];
    }
}

// K5: ph partials. wave w handles s = s0 + 4g + w -> hidden loads are lane-contiguous
// float4 (16B/lane), attn loads wave-uniform scalars. Cross-wave LDS reduce at end.
__global__ __launch_bounds__(256) void k5_phpart(const float* __restrict__ hidden,
                                                 const float* __restrict__ attn,
                                                 float* __restrict__ ws) {
    __shared__ float4 sh4[12 * 4 * 64];    // 48 KB
    int blk = blockIdx.x;              // 768 = 8 b * 3 ct * 32 sc
    int sc = blk & 31;
    int ct = (blk >> 5) % 3;
    int b = blk / 96;
    int tid = threadIdx.x;
    int w = tid >> 6, lane = tid & 63;
    int c = ct * 256 + lane * 4;
    int s0 = sc * 128;
    const float* hb = hidden + (size_t)(b * 4096 + s0) * 768 + c;
    const float* ab = attn + (size_t)b * 49152 + s0 + w;
    float4 acc[12];
#pragma unroll
    for (int h = 0; h < 12; ++h) acc[h] = make_float4(0.f, 0.f, 0.f, 0.f);
    for (int g = 0; g < 32; ++g) {
        float4 x = *reinterpret_cast<const float4*>(hb + (size_t)(g * 4 + w) * 768);
        float a[12];
#pragma unroll
        for (int h = 0; h < 12; ++h) a[h] = ab[h * 4096 + g * 4];
#pragma unroll
        for (int h = 0; h < 12; ++h) {
            acc[h].x += a[h] * x.x; acc[h].y += a[h] * x.y;
            acc[h].z += a[h] * x.z; acc[h].w += a[h] * x.w;
        }
    }
#pragma unroll
    for (int h = 0; h < 12; ++h) sh4[(h * 4 + w) * 64 + lane] = acc[h];
    __syncthreads();
    float* php = ws + O_PHP;
#pragma unroll
    for (int i = 0; i < 3; ++i) {
        int h = w * 3 + i;
        float4 a = sh4[(h * 4 + 0) * 64 + lane];
        float4 b2 = sh4[(h * 4 + 1) * 64 + lane];
        float4 c2 = sh4[(h * 4 + 2) * 64 + lane];
        float4 d = sh4[(h * 4 + 3) * 64 + lane];
        float4 r;
        r.x = (a.x + b2.x) + (c2.x + d.x);
        r.y = (a.y + b2.y) + (c2.y + d.y);
        r.z = (a.z + b2.z) + (c2.z + d.z);
        r.w = (a.w + b2.w) + (c2.w + d.w);
        *reinterpret_cast<float4*>(php + (size_t)(sc * 96 + b * 12 + h) * 768 + c) = r;
    }
}

// K7 (fused K6): ctx_part[cch][b][j] = sum_{c in chunk} ph[b,h(j),c] * Wv[c,j]
// where ph[b,h,c] = sum_sc php[sc][b*12+h][c] is reduced inline into LDS
// (each ph element consumed by exactly one block -> traffic-neutral fusion).
__global__ __launch_bounds__(256) void k7_ctxpart(const float* __restrict__ Wv,
                                                  float* __restrict__ ws) {
    __shared__ float phl[512];         // [b][cc] for h=jt, c-chunk
    int blk = blockIdx.x;              // 144 = 12 jt * 12 cch
    int jt = blk % 12, cch = blk / 12;
    int tid = threadIdx.x;
    const float* php = ws + O_PHP;
#pragma unroll
    for (int t = 0; t < 2; ++t) {
        int idx = t * 256 + tid;       // < 512
        int b = idx >> 6, cc = idx & 63;
        int c = cch * 64 + cc;
        const float* p = php + (size_t)(b * 12 + jt) * 768 + c;
        float s = 0.f;
#pragma unroll
        for (int sc = 0; sc < N_SC; ++sc) s += p[(size_t)sc * 73728];
        phl[idx] = s;
    }
    __syncthreads();
    int j = jt * 256 + tid;
    float acc[8];
#pragma unroll
    for (int b = 0; b < 8; ++b) acc[b] = 0.f;
    for (int cc = 0; cc < 64; ++cc) {
        int c = cch * 64 + cc;
        float wv = Wv[(size_t)c * 3072 + j];
#pragma unroll
        for (int b = 0; b < 8; ++b) acc[b] += phl[b * 64 + cc] * wv;
    }
#pragma unroll
    for (int b = 0; b < 8; ++b)
        ws[O_CTXP + (size_t)(cch * 8 + b) * 3072 + j] = acc[b];
}

// K8 (fused K7b): out_part[ich][b][j] = sum_{i in chunk} ctx[b][i]*Wp[i,j]
// where ctx[b][i] = bv[i] + sum_cch ctxp[cch][b][i] is reduced inline into LDS.
__global__ __launch_bounds__(256) void k8_outpart(const float* __restrict__ Wp,
                                                  const float* __restrict__ bv,
                                                  float* __restrict__ ws) {
    __shared__ float ctxl[512];        // [b][ii] for i-chunk
    int blk = blockIdx.x;              // 144 = 3 jt * 48 ich
    int jt = blk % 3, ich = blk / 3;
    int tid = threadIdx.x;
#pragma unroll
    for (int t = 0; t < 2; ++t) {
        int idx = t * 256 + tid;       // < 512
        int b = idx >> 6, ii = idx & 63;
        int i = ich * 64 + ii;
        float s = bv[i];
#pragma unroll
        for (int cch = 0; cch < N_CCH; ++cch)
            s += ws[O_CTXP + (size_t)(cch * 8 + b) * 3072 + i];
        ctxl[idx] = s;
    }
    __syncthreads();
    int j = jt * 256 + tid;
    float acc[8];
#pragma unroll
    for (int b = 0; b < 8; ++b) acc[b] = 0.f;
    for (int ii = 0; ii < 64; ++ii) {
        int i = ich * 64 + ii;
        float wp = Wp[(size_t)i * 768 + j];
#pragma unroll
        for (int b = 0; b < 8; ++b) acc[b] += ctxl[b * 64 + ii] * wp;
    }
#pragma unroll
    for (int b = 0; b < 8; ++b)
        ws[O_OUTP + (size_t)(ich * 8 + b) * 768 + j] = acc[b];
}

// K9: reduce out partials + bp, layernorm, write pooled
__global__ __launch_bounds__(256) void k9_ln(const float* __restrict__ bp,
                                             const float* __restrict__ ln_w,
                                             const float* __restrict__ ln_b,
                                             const float* __restrict__ ws,
                                             float* __restrict__ pooled) {
    __shared__ float sh[8];
    int b = blockIdx.x, tid = threadIdx.x;
    const float* op = ws + O_OUTP;
    float vals[3];
    float lsum = 0.f, lsq = 0.f;
#pragma unroll
    for (int t = 0; t < 3; ++t) {
        int j = t * 256 + tid;
        float v = bp[j];
#pragma unroll
        for (int ich = 0; ich < N_ICH; ++ich) v += op[(size_t)(ich * 8 + b) * 768 + j];
        vals[t] = v; lsum += v; lsq += v * v;
    }
    lsum = waveReduceSum(lsum);
    lsq = waveReduceSum(lsq);
    if ((tid & 63) == 0) { sh[tid >> 6] = lsum; sh[4 + (tid >> 6)] = lsq; }
    __syncthreads();
    float mean = (sh[0] + sh[1] + sh[2] + sh[3]) * (1.f / 768.f);
    float var = (sh[4] + sh[5] + sh[6] + sh[7]) * (1.f / 768.f) - mean * mean;
    float inv = rsqrtf(var + LN_EPS);
#pragma unroll
    for (int t = 0; t < 3; ++t) {
        int j = t * 256 + tid;
        pooled[b * 768 + j] = (vals[t] - mean) * inv * (ln_w[j] + 1.f) + ln_b[j];
    }
}

extern "C" void kernel_launch(void* const* d_in, const int* in_sizes, int n_in,
                              void* d_out, int out_size, void* d_ws, size_t ws_size,
                              hipStream_t stream) {
    const float* hidden = (const float*)d_in[0];
    const float* pq     = (const float*)d_in[1];
    const float* Wq     = (const float*)d_in[2];
    const float* bq     = (const float*)d_in[3];
    const float* Wk     = (const float*)d_in[4];
    const float* Wv     = (const float*)d_in[6];
    const float* bv     = (const float*)d_in[7];
    const float* Wp     = (const float*)d_in[8];
    const float* bp     = (const float*)d_in[9];
    const float* pds    = (const float*)d_in[10];
    const float* ln_w   = (const float*)d_in[11];
    const float* ln_b   = (const float*)d_in[12];
    float* out = (float*)d_out;
    float* ws  = (float*)d_ws;
    float* pooled = out;          // (8,1,768) = 6144 floats
    float* attn   = out + 6144;   // (8,12,1,4096) = 393216 floats

    k1_qpart   <<<288, 256, 0, stream>>>(pq, Wq, ws);
    k1b_qreduce<<<12, 256, 0, stream>>>(bq, pds, ws);
    k2_wkeff   <<<768, 256, 0, stream>>>(Wk, ws);
    k3_logits  <<<2048, 256, 0, stream>>>(hidden, ws);
    k4_softmax <<<96, 256, 0, stream>>>(ws, attn);
    k5_phpart  <<<768, 256, 0, stream>>>(hidden, attn, ws);
    k7_ctxpart <<<144, 256, 0, stream>>>(Wv, ws);
    k8_outpart <<<144, 256, 0, stream>>>(Wp, bv, ws);
    k9_ln      <<<8, 256, 0, stream>>>(bp, ln_w, ln_b, ws, pooled);
}

// Round 5
// 266.389 us; speedup vs baseline: 1.0619x; 1.0205x over previous
//
#include <hip/hip_runtime.h>
#include <cstdint>
#include <cmath>

#define LN_EPS 1e-6f

// ---- workspace layout (float offsets) ----
#define N_QCH 24u                      // q partial chunks (32 c each)
#define O_QPART 0u                     // [24][3072]
#define O_Q     73728u                 // [3072] scaled q
#define O_WK    76800u                 // wk_eff [768][12]
#define O_PLOG  86016u                 // partial logits [4][96][4096]
#define O_PHP   1658880u               // ph partials [32][96][768]
#define N_SC    32
#define O_CTXP  4091904u               // ctx partials [12][8][3072]
#define N_CCH   12
#define O_OUTP  4411392u               // out partials [48][8][768]
#define N_ICH   48
// end: 4706304 floats = 18.8 MB (ws is ~384 MiB)

__device__ __forceinline__ float waveReduceSum(float v) {
#pragma unroll
    for (int o = 32; o >= 1; o >>= 1) v += __shfl_xor(v, o, 64);
    return v;
}
__device__ __forceinline__ float waveReduceMax(float v) {
#pragma unroll
    for (int o = 32; o >= 1; o >>= 1) v = fmaxf(v, __shfl_xor(v, o, 64));
    return v;
}

// K1: q partials: q_part[ch][h*256+d] = sum_{c in chunk} pq[c]*Wq[c, h*256+d]
__global__ __launch_bounds__(256) void k1_qpart(const float* __restrict__ pq,
                                                const float* __restrict__ Wq,
                                                float* __restrict__ ws) {
    int h = blockIdx.x % 12;
    int ch = blockIdx.x / 12;          // 24 chunks of 32 c
    int tid = threadIdx.x;
    int col = h * 256 + tid;
    int c0 = ch * 32;
    float acc = 0.f;
#pragma unroll 8
    for (int i = 0; i < 32; ++i) {
        int c = c0 + i;
        acc += pq[c] * Wq[c * 3072 + col];
    }
    ws[O_QPART + ch * 3072 + col] = acc;
}

// K1b: reduce q partials, add bq, apply scale * softplus(per_dim_scale)
__global__ __launch_bounds__(256) void k1b_qreduce(const float* __restrict__ bq,
                                                   const float* __restrict__ pds,
                                                   float* __restrict__ ws) {
    int j = blockIdx.x * 256 + threadIdx.x;   // < 3072
    float acc = bq[j];
#pragma unroll
    for (unsigned ch = 0; ch < N_QCH; ++ch) acc += ws[O_QPART + ch * 3072 + j];
    float x = pds[j & 255];
    float sp = (x > 20.f) ? x : log1pf(expf(x));
    const float scale = 1.442695041f / 16.0f;  // r_softplus_0 / sqrt(256)
    ws[O_Q + j] = acc * scale * sp;
}

// K2: wk_eff[c][h] = sum_d Wk[c, h*256+d]*q[h,d]
// one block per c-row; wave w handles heads {3w, 3w+1, 3w+2} via float4 dots.
// (bk folds to a per-row softmax-invariant constant -> dropped)
__global__ __launch_bounds__(256) void k2_wkeff(const float* __restrict__ Wk,
                                                float* __restrict__ ws) {
    int c = blockIdx.x;                // 768
    int tid = threadIdx.x;
    int w = tid >> 6, lane = tid & 63;
    const float4* wk = reinterpret_cast<const float4*>(Wk + (size_t)c * 3072);
    const float4* qv = reinterpret_cast<const float4*>(ws + O_Q);
#pragma unroll
    for (int i = 0; i < 3; ++i) {
        int h = w * 3 + i;
        float4 a = wk[h * 64 + lane];
        float4 b = qv[h * 64 + lane];
        float d = a.x * b.x + a.y * b.y + a.z * b.z + a.w * b.w;
        d = waveReduceSum(d);
        if (lane == 0) ws[O_WK + c * 12 + h] = d;
    }
}

// K3: partial logits. block = (b, s-tile of 64 rows, c-quarter of 192).
// Double-buffered pipeline: 4 chunks of 48 c; per iter [store buf | issue next loads |
// ONE barrier | compute]. Loads stay in flight across the barrier; only 3 float4 of
// prefetch state live (no spills). XOR-(r&3) swizzle -> <=2-way LDS aliasing.
__global__ __launch_bounds__(256) void k3_logits(const float* __restrict__ hidden,
                                                 float* __restrict__ ws) {
    __shared__ float4 tile4[2][768];   // 2 x 12 KB: [buf][r*12 + (j^(r&3))]
    __shared__ float4 wkb4[576];       // 9 KB: 192 c x 12 h
    int blk = blockIdx.x;              // 2048 = 8 b * 64 stiles * 4 quarters
    int q = blk & 3;
    int st = (blk >> 2) & 63;
    int b = blk >> 8;
    int s0 = st * 64;
    const float* hb = hidden + (size_t)(b * 4096 + s0) * 768 + q * 192;
    const float4* wkg4 = reinterpret_cast<const float4*>(ws + O_WK);
    int tid = threadIdx.x;
    int w = tid >> 6, lane = tid & 63;
    // stage wk slice (192 c x 12 h = 576 f4)
    for (int i = tid; i < 576; i += 256) wkb4[i] = wkg4[q * 576 + i];
    // thread's 3 staging slots (fixed across chunks)
    int rr[3], jj[3];
#pragma unroll
    for (int t = 0; t < 3; ++t) {
        int idx = t * 256 + tid;       // < 768
        rr[t] = idx / 12;
        jj[t] = idx % 12;
    }
    // prefetch chunk 0
    float4 v[3];
#pragma unroll
    for (int t = 0; t < 3; ++t)
        v[t] = *reinterpret_cast<const float4*>(hb + rr[t] * 768 + jj[t] * 4);

    float acc[12];
#pragma unroll
    for (int h = 0; h < 12; ++h) acc[h] = 0.f;

    for (int ck = 0; ck < 4; ++ck) {
        float4* buf = tile4[ck & 1];
#pragma unroll
        for (int t = 0; t < 3; ++t)
            buf[rr[t] * 12 + (jj[t] ^ (rr[t] & 3))] = v[t];
        if (ck < 3) {
#pragma unroll
            for (int t = 0; t < 3; ++t)
                v[t] = *reinterpret_cast<const float4*>(hb + rr[t] * 768 + (ck + 1) * 48 + jj[t] * 4);
        }
        __syncthreads();
#pragma unroll
        for (int j2 = 0; j2 < 3; ++j2) {
            int jcol = w * 3 + j2;
            float4 x = buf[lane * 12 + (jcol ^ (lane & 3))];
            const float4* wr = &wkb4[(ck * 48 + jcol * 4) * 3];
            float xc[4] = {x.x, x.y, x.z, x.w};
#pragma unroll
            for (int cc = 0; cc < 4; ++cc) {
                float4 w0 = wr[cc * 3 + 0], w1 = wr[cc * 3 + 1], w2 = wr[cc * 3 + 2];
                acc[0] += xc[cc] * w0.x;  acc[1] += xc[cc] * w0.y;  acc[2]  += xc[cc] * w0.z;  acc[3]  += xc[cc] * w0.w;
                acc[4] += xc[cc] * w1.x;  acc[5] += xc[cc] * w1.y;  acc[6]  += xc[cc] * w1.z;  acc[7]  += xc[cc] * w1.w;
                acc[8] += xc[cc] * w2.x;  acc[9] += xc[cc] * w2.y;  acc[10] += xc[cc] * w2.z;  acc[11] += xc[cc] * w2.w;
            }
        }
        // no trailing barrier: buffer reused 2 iters later, separated by next iter's barrier
    }
    // epilogue: red aliases buf0 (3072 floats); last compute read buf1 -> disjoint
    float* red = reinterpret_cast<float*>(tile4);
#pragma unroll
    for (int h = 0; h < 12; ++h) red[(w * 12 + h) * 64 + lane] = acc[h];
    __syncthreads();
    float* plog = ws + O_PLOG;
    for (int idx = tid; idx < 768; idx += 256) {
        int h = idx / 64, r2 = idx & 63;
        float vv = red[(0 + h) * 64 + r2] + red[(12 + h) * 64 + r2] +
                   red[(24 + h) * 64 + r2] + red[(36 + h) * 64 + r2];
        plog[(size_t)q * 393216 + (size_t)(b * 12 + h) * 4096 + s0 + r2] = vv;
    }
}

// K4: sum the four c-quarter partials, softmax over s=4096, write attn to d_out
__global__ __launch_bounds__(256) void k4_softmax(const float* __restrict__ ws,
                                                  float* __restrict__ attn) {
    __shared__ float sh[4];
    int row = blockIdx.x;              // 96 = 8*12
    const float4* p0 = reinterpret_cast<const float4*>(ws + O_PLOG + (size_t)row * 4096);
    const float4* p1 = p0 + 98304;     // +393216 floats
    const float4* p2 = p0 + 196608;
    const float4* p3 = p0 + 294912;
    float* base = attn + (size_t)row * 4096;
    int tid = threadIdx.x;
    float4 x[4];
#pragma unroll
    for (int t = 0; t < 4; ++t) {
        float4 a = p0[t * 256 + tid], c = p1[t * 256 + tid];
        float4 d = p2[t * 256 + tid], e = p3[t * 256 + tid];
        x[t].x = (a.x + c.x) + (d.x + e.x);
        x[t].y = (a.y + c.y) + (d.y + e.y);
        x[t].z = (a.z + c.z) + (d.z + e.z);
        x[t].w = (a.w + c.w) + (d.w + e.w);
    }
    float m = -1e30f;
#pragma unroll
    for (int t = 0; t < 4; ++t)
        m = fmaxf(m, fmaxf(fmaxf(x[t].x, x[t].y), fmaxf(x[t].z, x[t].w)));
    m = waveReduceMax(m);
    if ((tid & 63) == 0) sh[tid >> 6] = m;
    __syncthreads();
    m = fmaxf(fmaxf(sh[0], sh[1]), fmaxf(sh[2], sh[3]));
    __syncthreads();
    float s = 0.f;
#pragma unroll
    for (int t = 0; t < 4; ++t) {
        x[t].x = expf(x[t].x - m); x[t].y = expf(x[t].y - m);
        x[t].z = expf(x[t].z - m); x[t].w = expf(x[t].w - m);
        s += x[t].x + x[t].y + x[t].z + x[t].w;
    }
    s = waveReduceSum(s);
    if ((tid & 63) == 0) sh[tid >> 6] = s;
    __syncthreads();
    s = sh[0] + sh[1] + sh[2] + sh[3];
    float inv = 1.0f / s;
#pragma unroll
    for (int t = 0; t < 4; ++t) {
        x[t].x *= inv; x[t].y *= inv; x[t].z *= inv; x[t].w *= inv;
        reinterpret_cast<float4*>(base)[t * 256 + tid] = x[t];
    }
}

// K5: ph partials. wave w handles s = s0 + 4g + w -> hidden loads are lane-contiguous
// float4 (16B/lane), attn loads wave-uniform scalars. Cross-wave LDS reduce at end.
__global__ __launch_bounds__(256) void k5_phpart(const float* __restrict__ hidden,
                                                 const float* __restrict__ attn,
                                                 float* __restrict__ ws) {
    __shared__ float4 sh4[12 * 4 * 64];    // 48 KB
    int blk = blockIdx.x;              // 768 = 8 b * 3 ct * 32 sc
    int sc = blk & 31;
    int ct = (blk >> 5) % 3;
    int b = blk / 96;
    int tid = threadIdx.x;
    int w = tid >> 6, lane = tid & 63;
    int c = ct * 256 + lane * 4;
    int s0 = sc * 128;
    const float* hb = hidden + (size_t)(b * 4096 + s0) * 768 + c;
    const float* ab = attn + (size_t)b * 49152 + s0 + w;
    float4 acc[12];
#pragma unroll
    for (int h = 0; h < 12; ++h) acc[h] = make_float4(0.f, 0.f, 0.f, 0.f);
    for (int g = 0; g < 32; ++g) {
        float4 x = *reinterpret_cast<const float4*>(hb + (size_t)(g * 4 + w) * 768);
        float a[12];
#pragma unroll
        for (int h = 0; h < 12; ++h) a[h] = ab[h * 4096 + g * 4];
#pragma unroll
        for (int h = 0; h < 12; ++h) {
            acc[h].x += a[h] * x.x; acc[h].y += a[h] * x.y;
            acc[h].z += a[h] * x.z; acc[h].w += a[h] * x.w;
        }
    }
#pragma unroll
    for (int h = 0; h < 12; ++h) sh4[(h * 4 + w) * 64 + lane] = acc[h];
    __syncthreads();
    float* php = ws + O_PHP;
#pragma unroll
    for (int i = 0; i < 3; ++i) {
        int h = w * 3 + i;
        float4 a = sh4[(h * 4 + 0) * 64 + lane];
        float4 b2 = sh4[(h * 4 + 1) * 64 + lane];
        float4 c2 = sh4[(h * 4 + 2) * 64 + lane];
        float4 d = sh4[(h * 4 + 3) * 64 + lane];
        float4 r;
        r.x = (a.x + b2.x) + (c2.x + d.x);
        r.y = (a.y + b2.y) + (c2.y + d.y);
        r.z = (a.z + b2.z) + (c2.z + d.z);
        r.w = (a.w + b2.w) + (c2.w + d.w);
        *reinterpret_cast<float4*>(php + (size_t)(sc * 96 + b * 12 + h) * 768 + c) = r;
    }
}

// K7 (fused K6): ctx_part[cch][b][j] = sum_{c in chunk} ph[b,h(j),c] * Wv[c,j]
// where ph[b,h,c] = sum_sc php[sc][b*12+h][c] is reduced inline into LDS.
__global__ __launch_bounds__(256) void k7_ctxpart(const float* __restrict__ Wv,
                                                  float* __restrict__ ws) {
    __shared__ float phl[512];         // [b][cc] for h=jt, c-chunk
    int blk = blockIdx.x;              // 144 = 12 jt * 12 cch
    int jt = blk % 12, cch = blk / 12;
    int tid = threadIdx.x;
    const float* php = ws + O_PHP;
#pragma unroll
    for (int t = 0; t < 2; ++t) {
        int idx = t * 256 + tid;       // < 512
        int b = idx >> 6, cc = idx & 63;
        int c = cch * 64 + cc;
        const float* p = php + (size_t)(b * 12 + jt) * 768 + c;
        float s = 0.f;
#pragma unroll
        for (int sc = 0; sc < N_SC; ++sc) s += p[(size_t)sc * 73728];
        phl[idx] = s;
    }
    __syncthreads();
    int j = jt * 256 + tid;
    float acc[8];
#pragma unroll
    for (int b = 0; b < 8; ++b) acc[b] = 0.f;
    for (int cc = 0; cc < 64; ++cc) {
        int c = cch * 64 + cc;
        float wv = Wv[(size_t)c * 3072 + j];
#pragma unroll
        for (int b = 0; b < 8; ++b) acc[b] += phl[b * 64 + cc] * wv;
    }
#pragma unroll
    for (int b = 0; b < 8; ++b)
        ws[O_CTXP + (size_t)(cch * 8 + b) * 3072 + j] = acc[b];
}

// K8 (fused K7b): out_part[ich][b][j] = sum_{i in chunk} ctx[b][i]*Wp[i,j]
// where ctx[b][i] = bv[i] + sum_cch ctxp[cch][b][i] is reduced inline into LDS.
__global__ __launch_bounds__(256) void k8_outpart(const float* __restrict__ Wp,
                                                  const float* __restrict__ bv,
                                                  float* __restrict__ ws) {
    __shared__ float ctxl[512];        // [b][ii] for i-chunk
    int blk = blockIdx.x;              // 144 = 3 jt * 48 ich
    int jt = blk % 3, ich = blk / 3;
    int tid = threadIdx.x;
#pragma unroll
    for (int t = 0; t < 2; ++t) {
        int idx = t * 256 + tid;       // < 512
        int b = idx >> 6, ii = idx & 63;
        int i = ich * 64 + ii;
        float s = bv[i];
#pragma unroll
        for (int cch = 0; cch < N_CCH; ++cch)
            s += ws[O_CTXP + (size_t)(cch * 8 + b) * 3072 + i];
        ctxl[idx] = s;
    }
    __syncthreads();
    int j = jt * 256 + tid;
    float acc[8];
#pragma unroll
    for (int b = 0; b < 8; ++b) acc[b] = 0.f;
    for (int ii = 0; ii < 64; ++ii) {
        int i = ich * 64 + ii;
        float wp = Wp[(size_t)i * 768 + j];
#pragma unroll
        for (int b = 0; b < 8; ++b) acc[b] += ctxl[b * 64 + ii] * wp;
    }
#pragma unroll
    for (int b = 0; b < 8; ++b)
        ws[O_OUTP + (size_t)(ich * 8 + b) * 768 + j] = acc[b];
}

// K9: reduce out partials + bp, layernorm, write pooled
__global__ __launch_bounds__(256) void k9_ln(const float* __restrict__ bp,
                                             const float* __restrict__ ln_w,
                                             const float* __restrict__ ln_b,
                                             const float* __restrict__ ws,
                                             float* __restrict__ pooled) {
    __shared__ float sh[8];
    int b = blockIdx.x, tid = threadIdx.x;
    const float* op = ws + O_OUTP;
    float vals[3];
    float lsum = 0.f, lsq = 0.f;
#pragma unroll
    for (int t = 0; t < 3; ++t) {
        int j = t * 256 + tid;
        float v = bp[j];
#pragma unroll
        for (int ich = 0; ich < N_ICH; ++ich) v += op[(size_t)(ich * 8 + b) * 768 + j];
        vals[t] = v; lsum += v; lsq += v * v;
    }
    lsum = waveReduceSum(lsum);
    lsq = waveReduceSum(lsq);
    if ((tid & 63) == 0) { sh[tid >> 6] = lsum; sh[4 + (tid >> 6)] = lsq; }
    __syncthreads();
    float mean = (sh[0] + sh[1] + sh[2] + sh[3]) * (1.f / 768.f);
    float var = (sh[4] + sh[5] + sh[6] + sh[7]) * (1.f / 768.f) - mean * mean;
    float inv = rsqrtf(var + LN_EPS);
#pragma unroll
    for (int t = 0; t < 3; ++t) {
        int j = t * 256 + tid;
        pooled[b * 768 + j] = (vals[t] - mean) * inv * (ln_w[j] + 1.f) + ln_b[j];
    }
}

extern "C" void kernel_launch(void* const* d_in, const int* in_sizes, int n_in,
                              void* d_out, int out_size, void* d_ws, size_t ws_size,
                              hipStream_t stream) {
    const float* hidden = (const float*)d_in[0];
    const float* pq     = (const float*)d_in[1];
    const float* Wq     = (const float*)d_in[2];
    const float* bq     = (const float*)d_in[3];
    const float* Wk     = (const float*)d_in[4];
    const float* Wv     = (const float*)d_in[6];
    const float* bv     = (const float*)d_in[7];
    const float* Wp     = (const float*)d_in[8];
    const float* bp     = (const float*)d_in[9];
    const float* pds    = (const float*)d_in[10];
    const float* ln_w   = (const float*)d_in[11];
    const float* ln_b   = (const float*)d_in[12];
    float* out = (float*)d_out;
    float* ws  = (float*)d_ws;
    float* pooled = out;          // (8,1,768) = 6144 floats
    float* attn   = out + 6144;   // (8,12,1,4096) = 393216 floats

    k1_qpart   <<<288, 256, 0, stream>>>(pq, Wq, ws);
    k1b_qreduce<<<12, 256, 0, stream>>>(bq, pds, ws);
    k2_wkeff   <<<768, 256, 0, stream>>>(Wk, ws);
    k3_logits  <<<2048, 256, 0, stream>>>(hidden, ws);
    k4_softmax <<<96, 256, 0, stream>>>(ws, attn);
    k5_phpart  <<<768, 256, 0, stream>>>(hidden, attn, ws);
    k7_ctxpart <<<144, 256, 0, stream>>>(Wv, ws);
    k8_outpart <<<144, 256, 0, stream>>>(Wp, bv, ws);
    k9_ln      <<<8, 256, 0, stream>>>(bp, ln_w, ln_b, ws, pooled);
}